// Round 1
// baseline (334.992 us; speedup 1.0000x reference)
//
#include <hip/hip_runtime.h>

// 2D DWT (db2, symmetric pad, pywt-compatible), fused row+col passes.
// x: (16,3,1024,1024) f32 -> cA, cH: (16,3,513,513) f32 each, concatenated in d_out.
//
// y[i] = sum_k f_rev[k] * xp[2i+k], xp = symmetric pad (2 left, 3 right),
// xp[p] -> x[refl(p)] with refl(p): r=p-2; r<0 -> -1-r; r>1023 -> 2047-r.

#define N 1024
#define NOUT 513
#define TI 32
#define TJ 32
#define NROWS (2*TI + 2)      // 66 xp-rows per tile
#define NCOLS 68              // raw cols loaded per tile (aligned to 16B)
#define NQUAD (NCOLS/4)       // 17 float4 per row
#define EO 33                 // even/odd array row length (66 cc values -> 33+33)

__device__ __forceinline__ int refl(int p) {
    int r = p - 2;
    r = (r < 0) ? (-1 - r) : r;
    r = (r > N - 1) ? (2 * N - 1 - r) : r;
    return r;
}

__global__ __launch_bounds__(256) void dwt2_fused(const float* __restrict__ x,
                                                  float* __restrict__ out) {
    // filt_rev for lo and hi (true convolution => reversed filter taps)
    const float lo_rev0 =  0.48296291314469025f;
    const float lo_rev1 =  0.836516303737469f;
    const float lo_rev2 =  0.22414386804185735f;
    const float lo_rev3 = -0.12940952255092145f;
    const float hi_rev0 = -0.12940952255092145f;
    const float hi_rev1 = -0.22414386804185735f;
    const float hi_rev2 =  0.836516303737469f;
    const float hi_rev3 = -0.48296291314469025f;

    __shared__ float xin[NROWS * NCOLS];        // 66*68*4 = 17952 B
    __shared__ float lo_e[TI * EO];             // 4224 B each
    __shared__ float lo_o[TI * EO];
    __shared__ float hi_e[TI * EO];
    __shared__ float hi_o[TI * EO];

    const int tj_blk = blockIdx.x;
    const int ti_blk = blockIdx.y;
    const int img    = blockIdx.z;
    const int i0 = ti_blk * TI;
    const int j0 = tj_blk * TJ;
    const int t  = threadIdx.x;

    const float* xim = x + (size_t)img * N * N;

    int cb = 2 * j0 - 4;                        // aligned raw-col base (mult of 4)
    if (cb < 0) cb = 0;                         // left-edge tile: reflection stays in [0,68)

    // ---- Stage 0: global -> LDS, float4 coalesced ----
    for (int v = t; v < NROWS * NQUAD; v += 256) {
        int rr = v / NQUAD;
        int q  = v - rr * NQUAD;
        int pr = 2 * i0 + rr;
        if (pr > N + 4) pr = N + 4;             // clamp xp row to 1028 (tail tile)
        int row = refl(pr);
        int c0 = cb + 4 * q;
        float4 val;
        if (c0 + 3 < N) {
            val = *reinterpret_cast<const float4*>(xim + (size_t)row * N + c0);
        } else {                                // only last col-tile: clamp (values unused)
            float tmp0, tmp1, tmp2, tmp3;
            int c;
            c = c0 + 0; if (c > N - 1) c = N - 1; tmp0 = xim[(size_t)row * N + c];
            c = c0 + 1; if (c > N - 1) c = N - 1; tmp1 = xim[(size_t)row * N + c];
            c = c0 + 2; if (c > N - 1) c = N - 1; tmp2 = xim[(size_t)row * N + c];
            c = c0 + 3; if (c > N - 1) c = N - 1; tmp3 = xim[(size_t)row * N + c];
            val = make_float4(tmp0, tmp1, tmp2, tmp3);
        }
        *reinterpret_cast<float4*>(&xin[rr * NCOLS + 4 * q]) = val;
    }
    __syncthreads();

    // ---- Stage 1: row transform (axis -2), de-interleave even/odd cc ----
    for (int w = t; w < TI * 66; w += 256) {
        int ti = w / 66;
        int cc = w - ti * 66;
        int pc = 2 * j0 + cc;
        if (pc > N + 4) pc = N + 4;             // clamp xp col to 1028 (tail tile)
        int lc = refl(pc) - cb;                 // LDS col (interior: cc+2)
        float a0 = xin[(2 * ti + 0) * NCOLS + lc];
        float a1 = xin[(2 * ti + 1) * NCOLS + lc];
        float a2 = xin[(2 * ti + 2) * NCOLS + lc];
        float a3 = xin[(2 * ti + 3) * NCOLS + lc];
        float lo = lo_rev0 * a0 + lo_rev1 * a1 + lo_rev2 * a2 + lo_rev3 * a3;
        float hi = hi_rev0 * a0 + hi_rev1 * a1 + hi_rev2 * a2 + hi_rev3 * a3;
        int e = cc >> 1;
        if (cc & 1) { lo_o[ti * EO + e] = lo; hi_o[ti * EO + e] = hi; }
        else        { lo_e[ti * EO + e] = lo; hi_e[ti * EO + e] = hi; }
    }
    __syncthreads();

    // ---- Stage 2: column transform (lo taps for both outputs) + store ----
    const size_t plane = (size_t)NOUT * NOUT;
    float* cA = out + (size_t)img * plane;
    float* cH = out + (size_t)48 * plane + (size_t)img * plane;
    for (int w = t; w < TI * TJ; w += 256) {
        int ti = w >> 5;
        int tj = w & 31;
        int i = i0 + ti;
        int j = j0 + tj;
        if (i < NOUT && j < NOUT) {
            // cc = 2*tj + k: k=0 -> even[tj], k=1 -> odd[tj], k=2 -> even[tj+1], k=3 -> odd[tj+1]
            float e0 = lo_e[ti * EO + tj];
            float o0 = lo_o[ti * EO + tj];
            float e1 = lo_e[ti * EO + tj + 1];
            float o1 = lo_o[ti * EO + tj + 1];
            float vA = lo_rev0 * e0 + lo_rev1 * o0 + lo_rev2 * e1 + lo_rev3 * o1;
            float f0 = hi_e[ti * EO + tj];
            float g0 = hi_o[ti * EO + tj];
            float f1 = hi_e[ti * EO + tj + 1];
            float g1 = hi_o[ti * EO + tj + 1];
            float vH = lo_rev0 * f0 + lo_rev1 * g0 + lo_rev2 * f1 + lo_rev3 * g1;
            cA[(size_t)i * NOUT + j] = vA;
            cH[(size_t)i * NOUT + j] = vH;
        }
    }
}

extern "C" void kernel_launch(void* const* d_in, const int* in_sizes, int n_in,
                              void* d_out, int out_size, void* d_ws, size_t ws_size,
                              hipStream_t stream) {
    (void)in_sizes; (void)n_in; (void)d_ws; (void)ws_size; (void)out_size;
    const float* x = (const float*)d_in[0];
    float* out = (float*)d_out;
    dim3 grid((NOUT + TJ - 1) / TJ, (NOUT + TI - 1) / TI, 48);   // 17 x 17 x 48
    dim3 block(256);
    dwt2_fused<<<grid, block, 0, stream>>>(x, out);
}

// Round 2
// 312.662 us; speedup vs baseline: 1.0714x; 1.0714x over previous
//
#include <hip/hip_runtime.h>

// 2D DWT (db2, symmetric pad, pywt-compatible), strip-fused.
// x: (16,3,1024,1024) f32 -> cA, cH: (16,3,513,513) f32, concatenated in d_out.
//
// Pass 1 (axis -2, vertical): per-column, registers only, coalesced float4.
// Pass 2 (axis -1, horizontal): via LDS row buffers (ping-pong, 1 barrier/row).
// y[i] = sum_k f_rev[k] * xp[2i+k]; xp[p] -> x[refl(p)], refl: r=p-2;
// r<0 -> -1-r; r>1023 -> 2047-r.

#define N 1024
#define NOUT 513
#define TI 8                   // output rows per block
#define STRIPS ((NOUT + TI - 1) / TI)   // 65

__device__ __forceinline__ int refl(int p) {
    int r = p - 2;
    r = (r < 0) ? (-1 - r) : r;
    r = (r > N - 1) ? (2 * N - 1 - r) : r;
    return r;
}

__global__ __launch_bounds__(256, 8) void dwt2_strip(const float* __restrict__ x,
                                                     float* __restrict__ out) {
    // reversed filter taps (true convolution)
    const float l0 =  0.48296291314469025f;
    const float l1 =  0.836516303737469f;
    const float l2 =  0.22414386804185735f;
    const float l3 = -0.12940952255092145f;
    const float h0 = -0.12940952255092145f;
    const float h1 = -0.22414386804185735f;
    const float h2 =  0.836516303737469f;
    const float h3 = -0.48296291314469025f;

    __shared__ float sLo[2][N];   // ping-pong row buffers: 2*4KB
    __shared__ float sHi[2][N];   // 2*4KB  (16.4 KB total -> 8 blocks/CU)

    const int strip = blockIdx.x;
    const int img   = blockIdx.y;
    const int i0 = strip * TI;
    const int t  = threadIdx.x;
    const int c  = 4 * t;                       // column base (0..1020)

    const float* xim = x + (size_t)img * N * N;
    const size_t plane = (size_t)NOUT * NOUT;
    float* cA = out + (size_t)img * plane;
    float* cH = out + ((size_t)48 + img) * plane;

    const int nrows = (NOUT - i0 < TI) ? (NOUT - i0) : TI;

    // prologue: carry rows xp[2*i0], xp[2*i0+1]; prefetch xp[2*i0+2..3]
    float4 r0 = *reinterpret_cast<const float4*>(xim + (size_t)refl(2 * i0)     * N + c);
    float4 r1 = *reinterpret_cast<const float4*>(xim + (size_t)refl(2 * i0 + 1) * N + c);
    float4 n0 = *reinterpret_cast<const float4*>(xim + (size_t)refl(2 * i0 + 2) * N + c);
    float4 n1 = *reinterpret_cast<const float4*>(xim + (size_t)refl(2 * i0 + 3) * N + c);

    for (int ii = 0; ii < nrows; ++ii) {
        const int i = i0 + ii;
        const int buf = ii & 1;

        // ---- vertical transform for output row i (registers -> LDS) ----
        float4 lo, hi;
        lo.x = l0 * r0.x + l1 * r1.x + l2 * n0.x + l3 * n1.x;
        lo.y = l0 * r0.y + l1 * r1.y + l2 * n0.y + l3 * n1.y;
        lo.z = l0 * r0.z + l1 * r1.z + l2 * n0.z + l3 * n1.z;
        lo.w = l0 * r0.w + l1 * r1.w + l2 * n0.w + l3 * n1.w;
        hi.x = h0 * r0.x + h1 * r1.x + h2 * n0.x + h3 * n1.x;
        hi.y = h0 * r0.y + h1 * r1.y + h2 * n0.y + h3 * n1.y;
        hi.z = h0 * r0.z + h1 * r1.z + h2 * n0.z + h3 * n1.z;
        hi.w = h0 * r0.w + h1 * r1.w + h2 * n0.w + h3 * n1.w;
        *reinterpret_cast<float4*>(&sLo[buf][c]) = lo;
        *reinterpret_cast<float4*>(&sHi[buf][c]) = hi;
        r0 = n0;
        r1 = n1;

        __syncthreads();   // V(ii) visible; also fences H(ii-1) before next overwrite

        // ---- prefetch next row pair (overlaps horizontal phase) ----
        if (ii + 1 < nrows) {
            const int ip = i + 1;
            n0 = *reinterpret_cast<const float4*>(xim + (size_t)refl(2 * ip + 2) * N + c);
            n1 = *reinterpret_cast<const float4*>(xim + (size_t)refl(2 * ip + 3) * N + c);
        }

        // ---- horizontal transform + store (513 outputs x 2 filters) ----
        const float* __restrict__ Lrow = sLo[buf];
        const float* __restrict__ Hrow = sHi[buf];
        for (int j = t; j < NOUT; j += 256) {
            float a0, a1, a2, a3, b0, b1, b2, b3;
            if (j >= 1 && j <= NOUT - 2) {
                const int cc = 2 * j - 2;
                a0 = Lrow[cc]; a1 = Lrow[cc + 1]; a2 = Lrow[cc + 2]; a3 = Lrow[cc + 3];
                b0 = Hrow[cc]; b1 = Hrow[cc + 1]; b2 = Hrow[cc + 2]; b3 = Hrow[cc + 3];
            } else {
                const int c0 = refl(2 * j), c1 = refl(2 * j + 1);
                const int c2 = refl(2 * j + 2), c3 = refl(2 * j + 3);
                a0 = Lrow[c0]; a1 = Lrow[c1]; a2 = Lrow[c2]; a3 = Lrow[c3];
                b0 = Hrow[c0]; b1 = Hrow[c1]; b2 = Hrow[c2]; b3 = Hrow[c3];
            }
            cA[(size_t)i * NOUT + j] = l0 * a0 + l1 * a1 + l2 * a2 + l3 * a3;
            cH[(size_t)i * NOUT + j] = l0 * b0 + l1 * b1 + l2 * b2 + l3 * b3;
        }
    }
}

extern "C" void kernel_launch(void* const* d_in, const int* in_sizes, int n_in,
                              void* d_out, int out_size, void* d_ws, size_t ws_size,
                              hipStream_t stream) {
    (void)in_sizes; (void)n_in; (void)d_ws; (void)ws_size; (void)out_size;
    const float* x = (const float*)d_in[0];
    float* out = (float*)d_out;
    dim3 grid(STRIPS, 48);    // 65 x 48 = 3120 blocks
    dim3 block(256);
    dwt2_strip<<<grid, block, 0, stream>>>(x, out);
}